// Round 9
// baseline (92.603 us; speedup 1.0000x reference)
//
#include <hip/hip_runtime.h>

// QSP via Laurent polynomial, single fused kernel.
// u00(theta) = sum_{t=0..127} gamma_t e^{i(2t-127)theta}; gamma depends only on phis.
// Compressed recurrence (j=(m+k)/2 in [0,k], validated R6-R8):
//   A'[j] = e_k  * 0.5*(A[j-1] + A[j] + B[j-1] - B[j])
//   B'[j] = ek^* * 0.5*(A[j-1] - A[j] + B[j-1] + B[j])
// R9: occupancy push. block=256 (4 waves), 4 elems/thread, grid=2048
// (8 blocks/CU -> 32 waves/CU = 100%). Setup = packed v2f + DPP wave_shr:1
// (cheap enough to replicate 2048x: ~25 instr/iter). Horner reads coeffs as
// float4 (2 gammas) from LDS, broadcast.

typedef float v2f __attribute__((ext_vector_type(2)));

#define NPHI 128

__device__ __forceinline__ float wave_shr1(float x) {
    // lane L <- lane L-1, lane 0 <- 0 (DPP wave_shr:1, bound_ctrl=1)
    return __builtin_bit_cast(float,
        __builtin_amdgcn_update_dpp(0, __builtin_bit_cast(int, x),
                                    0x138, 0xf, 0xf, true));
}

__global__ __launch_bounds__(256) void qsp_fused(
    const float* __restrict__ th,
    const float* __restrict__ phis,
    float* __restrict__ out,    // [0,B): real, [B,2B): imag
    int Bq)                      // B/4
{
    __shared__ alignas(16) float2 g2[NPHI];   // gamma_t
    __shared__ float2 h[NPHI];                // 0.5 * e^{i phi_k}

    const int tid = threadIdx.x;

    if (tid < 64) {
        const int L = tid;
        float sp, cp;
        __sincosf(phis[L], &sp, &cp);
        h[L] = make_float2(0.5f * cp, 0.5f * sp);
        __sincosf(phis[L + 64], &sp, &cp);
        h[L + 64] = make_float2(0.5f * cp, 0.5f * sp);
        // same-wave DS ordering: reads below see these writes

        // lane L holds slots j=2L, j=2L+1; (re,im) packed in v2f
        v2f A0 = {0.f, 0.f}, B0 = {0.f, 0.f};
        v2f A1 = {0.f, 0.f}, B1 = {0.f, 0.f};
        const float2 h0 = h[0];
        if (L == 0) A0 = (v2f){2.f * h0.x, 2.f * h0.y};   // A[0] = e_0

        #pragma unroll 4
        for (int k = 1; k < NPHI; ++k) {
            const float2 hk = h[k];          // broadcast, off critical path
            const v2f hx  = {hk.x, hk.x};
            const v2f hyn = {-hk.y, hk.y};   // e_k ⊛ t
            const v2f hyp = {hk.y, -hk.y};   // conj(e_k) ⊛ t
            const v2f pA = { wave_shr1(A1.x), wave_shr1(A1.y) };
            const v2f pB = { wave_shr1(B1.x), wave_shr1(B1.y) };
            const v2f u0 = pA + pB, v0 = A0 - B0;
            const v2f sA0 = u0 + v0, sB0 = u0 - v0;
            const v2f u1 = A0 + B0, v1 = A1 - B1;
            const v2f sA1 = u1 + v1, sB1 = u1 - v1;
            v2f ts;
            ts = (v2f){sA0.y, sA0.x};
            A0 = __builtin_elementwise_fma(hyn, ts, hx * sA0);
            ts = (v2f){sB0.y, sB0.x};
            B0 = __builtin_elementwise_fma(hyp, ts, hx * sB0);
            ts = (v2f){sA1.y, sA1.x};
            A1 = __builtin_elementwise_fma(hyn, ts, hx * sA1);
            ts = (v2f){sB1.y, sB1.x};
            B1 = __builtin_elementwise_fma(hyp, ts, hx * sB1);
        }
        g2[2 * L]     = make_float2(A0.x, A0.y);   // gamma_{2L}
        g2[2 * L + 1] = make_float2(A1.x, A1.y);   // gamma_{2L+1}
    }

    // ---- prologue: gamma-independent, overlaps wave 0's setup ----
    const int idx = blockIdx.x * blockDim.x + tid;
    const int lidx = (idx < Bq) ? idx : 0;
    const float4 t4 = ((const float4*)th)[lidx];

    v2f zr[2], zi[2], nzi[2];
    {
        float s0, c0, s1, c1;
        __sincosf(2.f * t4.x, &s0, &c0);
        __sincosf(2.f * t4.y, &s1, &c1);
        zr[0] = (v2f){c0, c1}; zi[0] = (v2f){s0, s1}; nzi[0] = (v2f){-s0, -s1};
        __sincosf(2.f * t4.z, &s0, &c0);
        __sincosf(2.f * t4.w, &s1, &c1);
        zr[1] = (v2f){c0, c1}; zi[1] = (v2f){s0, s1}; nzi[1] = (v2f){-s0, -s1};
    }

    __syncthreads();

    // ---- Horner in z = e^{2 i theta}, 128 steps (t=127..0), acc starts 0 ----
    v2f ar[2] = {{0.f,0.f},{0.f,0.f}};
    v2f ai[2] = {{0.f,0.f},{0.f,0.f}};
    const float4* g4 = (const float4*)g2;

    #pragma unroll 4
    for (int jj = NPHI / 2 - 1; jj >= 0; --jj) {
        const float4 gp = g4[jj];   // {g_{2jj}.re, .im, g_{2jj+1}.re, .im}
        {   // t = 2jj+1
            const v2f gr = {gp.z, gp.z}, gi = {gp.w, gp.w};
            #pragma unroll
            for (int g = 0; g < 2; ++g) {
                const v2f nr = __builtin_elementwise_fma(
                    ar[g], zr[g], __builtin_elementwise_fma(ai[g], nzi[g], gr));
                const v2f ni = __builtin_elementwise_fma(
                    ar[g], zi[g], __builtin_elementwise_fma(ai[g], zr[g], gi));
                ar[g] = nr; ai[g] = ni;
            }
        }
        {   // t = 2jj
            const v2f gr = {gp.x, gp.x}, gi = {gp.y, gp.y};
            #pragma unroll
            for (int g = 0; g < 2; ++g) {
                const v2f nr = __builtin_elementwise_fma(
                    ar[g], zr[g], __builtin_elementwise_fma(ai[g], nzi[g], gr));
                const v2f ni = __builtin_elementwise_fma(
                    ar[g], zi[g], __builtin_elementwise_fma(ai[g], zr[g], gi));
                ar[g] = nr; ai[g] = ni;
            }
        }
    }

    // ---- multiply by e^{-127 i theta}, store ----
    v2f Cc[2], Ss[2];
    {
        float s0, c0, s1, c1;
        __sincosf(127.f * t4.x, &s0, &c0);
        __sincosf(127.f * t4.y, &s1, &c1);
        Cc[0] = (v2f){c0, c1}; Ss[0] = (v2f){s0, s1};
        __sincosf(127.f * t4.z, &s0, &c0);
        __sincosf(127.f * t4.w, &s1, &c1);
        Cc[1] = (v2f){c0, c1}; Ss[1] = (v2f){s0, s1};
    }

    if (idx < Bq) {
        const v2f or0 = __builtin_elementwise_fma(ar[0], Cc[0], ai[0] * Ss[0]);
        const v2f oi0 = __builtin_elementwise_fma(ai[0], Cc[0], -(ar[0] * Ss[0]));
        const v2f or1 = __builtin_elementwise_fma(ar[1], Cc[1], ai[1] * Ss[1]);
        const v2f oi1 = __builtin_elementwise_fma(ai[1], Cc[1], -(ar[1] * Ss[1]));
        float4* o4 = (float4*)out;
        o4[idx]      = make_float4(or0.x, or0.y, or1.x, or1.y);
        o4[idx + Bq] = make_float4(oi0.x, oi0.y, oi1.x, oi1.y);
    }
}

extern "C" void kernel_launch(void* const* d_in, const int* in_sizes, int n_in,
                              void* d_out, int out_size, void* d_ws, size_t ws_size,
                              hipStream_t stream)
{
    const float* th   = (const float*)d_in[0];
    const float* phis = (const float*)d_in[1];
    float* out = (float*)d_out;
    const int B = in_sizes[0];          // 2097152
    const int Bq = B >> 2;              // 524288 threads
    const int block = 256;              // 4 waves
    const int grid = (Bq + block - 1) / block;   // 2048 blocks = 8/CU, 32 waves/CU
    qsp_fused<<<grid, block, 0, stream>>>(th, phis, out, Bq);
}

// Round 10
// 87.832 us; speedup vs baseline: 1.0543x; 1.0543x over previous
//
#include <hip/hip_runtime.h>

// QSP via Laurent polynomial, single fused kernel.
// u00(theta) = sum_{t=0..127} gamma_t e^{i(2t-127)theta}; gamma depends only on phis.
// Compressed recurrence (j=(m+k)/2 in [0,k], validated R6-R9):
//   A'[j] = e_k  * 0.5*(A[j-1] + A[j] + B[j-1] - B[j])
//   B'[j] = ek^* * 0.5*(A[j-1] - A[j] + B[j-1] + B[j])
// R10: PURE SCALAR hot code (no ext_vector ops -> no splat/swizzle mov bloat;
// negations fold into v_fma neg modifiers). 8 elems/thread, block=256,
// grid=1024 (16 waves/CU, 1024 setup copies). Rotating ds_read_b128 prefetch.

#define NPHI 128

__device__ __forceinline__ float wave_shr1(float x) {
    // lane L <- lane L-1, lane 0 <- 0 (DPP wave_shr:1, bound_ctrl=1)
    return __builtin_bit_cast(float,
        __builtin_amdgcn_update_dpp(0, __builtin_bit_cast(int, x),
                                    0x138, 0xf, 0xf, true));
}

__global__ __launch_bounds__(256, 4) void qsp_fused(
    const float* __restrict__ th,
    const float* __restrict__ phis,
    float* __restrict__ out,    // [0,B): real, [B,2B): imag
    int Bq8)                     // B/8
{
    __shared__ alignas(16) float2 g2[NPHI];   // gamma_t
    __shared__ float2 h[NPHI];                // 0.5 * e^{i phi_k}

    const int tid = threadIdx.x;

    if (tid < 64) {
        const int L = tid;
        float sp, cp;
        __sincosf(phis[L], &sp, &cp);
        h[L] = make_float2(0.5f * cp, 0.5f * sp);
        __sincosf(phis[L + 64], &sp, &cp);
        h[L + 64] = make_float2(0.5f * cp, 0.5f * sp);
        // same-wave DS ordering: reads below see these writes

        // lane L holds slots j=2L (A0/B0), j=2L+1 (A1/B1), scalar re/im
        float A0r = 0.f, A0i = 0.f, B0r = 0.f, B0i = 0.f;
        float A1r = 0.f, A1i = 0.f, B1r = 0.f, B1i = 0.f;
        const float2 h0 = h[0];
        if (L == 0) { A0r = 2.f * h0.x; A0i = 2.f * h0.y; }   // A[0] = e_0

        #pragma unroll 4
        for (int k = 1; k < NPHI; ++k) {
            const float2 hk = h[k];          // broadcast, off critical path
            const float hx = hk.x, hy = hk.y;
            // neighbor j-1 for slot0 = lane L-1's slot1 (DPP, lane0 -> 0)
            const float pAr = wave_shr1(A1r), pAi = wave_shr1(A1i);
            const float pBr = wave_shr1(B1r), pBi = wave_shr1(B1i);
            // butterflies (0.5 folded into h)
            const float u0r = pAr + pBr, u0i = pAi + pBi;
            const float v0r = A0r - B0r, v0i = A0i - B0i;
            const float sA0r = u0r + v0r, sA0i = u0i + v0i;
            const float sB0r = u0r - v0r, sB0i = u0i - v0i;
            const float u1r = A0r + B0r, u1i = A0i + B0i;
            const float v1r = A1r - B1r, v1i = A1i - B1i;
            const float sA1r = u1r + v1r, sA1i = u1i + v1i;
            const float sB1r = u1r - v1r, sB1i = u1i - v1i;
            // rotations: A <- e_k * sA ; B <- conj(e_k) * sB  (scalar FMA)
            A0r = fmaf(hx, sA0r, -hy * sA0i);
            A0i = fmaf(hx, sA0i,  hy * sA0r);
            B0r = fmaf(hx, sB0r,  hy * sB0i);
            B0i = fmaf(hx, sB0i, -hy * sB0r);
            A1r = fmaf(hx, sA1r, -hy * sA1i);
            A1i = fmaf(hx, sA1i,  hy * sA1r);
            B1r = fmaf(hx, sB1r,  hy * sB1i);
            B1i = fmaf(hx, sB1i, -hy * sB1r);
        }
        // gamma_{2L}, gamma_{2L+1} -> one ds_write_b128
        ((float4*)g2)[L] = make_float4(A0r, A0i, A1r, A1i);
    }

    // ---- prologue: gamma-independent, overlaps wave 0's setup ----
    const int idx = blockIdx.x * blockDim.x + tid;
    const int lidx = (idx < Bq8) ? idx : 0;
    const float4 ta = ((const float4*)th)[2 * lidx];
    const float4 tb = ((const float4*)th)[2 * lidx + 1];
    const float th8[8] = {ta.x, ta.y, ta.z, ta.w, tb.x, tb.y, tb.z, tb.w};

    float zr[8], zi[8];
    #pragma unroll
    for (int e = 0; e < 8; ++e) {
        float s, c;
        __sincosf(2.f * th8[e], &s, &c);
        zr[e] = c; zi[e] = s;
    }

    __syncthreads();

    // ---- Horner in z = e^{2 i theta}, t = 127..0, acc starts 0 ----
    float ar[8], ai[8];
    #pragma unroll
    for (int e = 0; e < 8; ++e) { ar[e] = 0.f; ai[e] = 0.f; }

    const float4* g4 = (const float4*)g2;
    float4 gp = g4[NPHI / 2 - 1];

    #pragma unroll 4
    for (int jj = NPHI / 2 - 1; jj >= 1; --jj) {
        const float4 gn = g4[jj - 1];    // prefetch next pair (independent)
        #pragma unroll
        for (int e = 0; e < 8; ++e) {    // t = 2jj+1: g = (gp.z, gp.w)
            const float nr = fmaf(ar[e], zr[e], fmaf(-ai[e], zi[e], gp.z));
            const float ni = fmaf(ar[e], zi[e], fmaf( ai[e], zr[e], gp.w));
            ar[e] = nr; ai[e] = ni;
        }
        #pragma unroll
        for (int e = 0; e < 8; ++e) {    // t = 2jj: g = (gp.x, gp.y)
            const float nr = fmaf(ar[e], zr[e], fmaf(-ai[e], zi[e], gp.x));
            const float ni = fmaf(ar[e], zi[e], fmaf( ai[e], zr[e], gp.y));
            ar[e] = nr; ai[e] = ni;
        }
        gp = gn;
    }
    #pragma unroll
    for (int e = 0; e < 8; ++e) {        // t = 1
        const float nr = fmaf(ar[e], zr[e], fmaf(-ai[e], zi[e], gp.z));
        const float ni = fmaf(ar[e], zi[e], fmaf( ai[e], zr[e], gp.w));
        ar[e] = nr; ai[e] = ni;
    }
    #pragma unroll
    for (int e = 0; e < 8; ++e) {        // t = 0
        const float nr = fmaf(ar[e], zr[e], fmaf(-ai[e], zi[e], gp.x));
        const float ni = fmaf(ar[e], zi[e], fmaf( ai[e], zr[e], gp.y));
        ar[e] = nr; ai[e] = ni;
    }

    // ---- multiply by e^{-127 i theta}: re = ar*C + ai*S, im = ai*C - ar*S ----
    float orv[8], oiv[8];
    #pragma unroll
    for (int e = 0; e < 8; ++e) {
        float S, C;
        __sincosf(127.f * th8[e], &S, &C);
        orv[e] = fmaf(ar[e], C,  ai[e] * S);
        oiv[e] = fmaf(ai[e], C, -ar[e] * S);
    }

    if (idx < Bq8) {
        float4* o4 = (float4*)out;
        const int ib = 2 * Bq8;   // imag base in float4 units (= B/4)
        o4[2 * idx]          = make_float4(orv[0], orv[1], orv[2], orv[3]);
        o4[2 * idx + 1]      = make_float4(orv[4], orv[5], orv[6], orv[7]);
        o4[ib + 2 * idx]     = make_float4(oiv[0], oiv[1], oiv[2], oiv[3]);
        o4[ib + 2 * idx + 1] = make_float4(oiv[4], oiv[5], oiv[6], oiv[7]);
    }
}

extern "C" void kernel_launch(void* const* d_in, const int* in_sizes, int n_in,
                              void* d_out, int out_size, void* d_ws, size_t ws_size,
                              hipStream_t stream)
{
    const float* th   = (const float*)d_in[0];
    const float* phis = (const float*)d_in[1];
    float* out = (float*)d_out;
    const int B = in_sizes[0];          // 2097152
    const int Bq8 = B >> 3;             // 262144 threads
    const int block = 256;              // 4 waves
    const int grid = (Bq8 + block - 1) / block;   // 1024 blocks = 4/CU, 16 waves/CU
    qsp_fused<<<grid, block, 0, stream>>>(th, phis, out, Bq8);
}